// Round 1
// baseline (1146.172 us; speedup 1.0000x reference)
//
#include <hip/hip_runtime.h>
#include <math.h>

// ---------------------------------------------------------------------------
// KAN forward, fp32 baseline.
//   h0 = [sin(x*f_l), cos(x*f_l)]            (N,32)
//   per layer: h = silu(h) @ bw^T + B(h) @ (sw*ss)^T
// Augmented-K GEMM: K = 9*F per layer (8 spline bases + silu per feature),
// expansion done on the fly into LDS, weights prefolded+transposed into ws.
// ---------------------------------------------------------------------------

#define N_PTS 32768
#define NOUT  256
#define BM    64      // rows per block
#define FC    32      // features per K-chunk
#define KC    288     // 9*FC augmented K per chunk

// ws layout (float offsets)
#define WT0_OFF 0                              // 288*256   = 73728
#define WT1_OFF 73728                          // 2304*256  = 589824
#define WT2_OFF (WT1_OFF + 589824)             // 589824
#define H0_OFF  (WT2_OFF + 589824)             // 32768*32  = 1048576
#define HA_OFF  (H0_OFF + 1048576)             // 32768*256 = 8388608
#define HB_OFF  (HA_OFF + 8388608)             // 8388608
// total = 19,079,168 floats = 76.3 MB

// knots: grid[j] = (j-3)*0.4f - 1.0f  (fp32, same ops as reference)
__device__ __forceinline__ float knotf(int j) { return (float)(j - 3) * 0.4f - 1.0f; }

// Cox-de Boor order-3, uniform knots; divisions constant-folded to multiplies.
__device__ __forceinline__ void spline8(float x, float b[8]) {
    float b0[11];
#pragma unroll
    for (int j = 0; j < 11; ++j)
        b0[j] = (x >= knotf(j) && x < knotf(j + 1)) ? 1.0f : 0.0f;
    float b1[10];
#pragma unroll
    for (int j = 0; j < 10; ++j)
        b1[j] = (x - knotf(j)) * (1.0f / (knotf(j + 1) - knotf(j))) * b0[j]
              + (knotf(j + 2) - x) * (1.0f / (knotf(j + 2) - knotf(j + 1))) * b0[j + 1];
    float b2[9];
#pragma unroll
    for (int j = 0; j < 9; ++j)
        b2[j] = (x - knotf(j)) * (1.0f / (knotf(j + 2) - knotf(j))) * b1[j]
              + (knotf(j + 3) - x) * (1.0f / (knotf(j + 3) - knotf(j + 1))) * b1[j + 1];
#pragma unroll
    for (int j = 0; j < 8; ++j)
        b[j]  = (x - knotf(j)) * (1.0f / (knotf(j + 3) - knotf(j))) * b2[j]
              + (knotf(j + 4) - x) * (1.0f / (knotf(j + 4) - knotf(j + 1))) * b2[j + 1];
}

__device__ __forceinline__ float silu_f(float x) { return x / (1.0f + expf(-x)); }

// ---------------------------------------------------------------------------
__global__ void encode_kernel(const float* __restrict__ x,
                              const float* __restrict__ freq,
                              float* __restrict__ h0) {
    int n = blockIdx.x * blockDim.x + threadIdx.x;
    if (n >= N_PTS) return;
    float xv = x[n];
#pragma unroll
    for (int l = 0; l < 16; ++l) {
        float e = xv * freq[l];
        h0[n * 32 + l]      = sinf(e);
        h0[n * 32 + 16 + l] = cosf(e);
    }
}

// Fold sw*ss and bw into Wt (9F, 256), chunk-contiguous K ordering:
// kg = chunk*288 + lk; lk<256 -> basis (f = chunk*32 + lk/8, j = lk%8),
// lk>=256 -> silu weight of feature chunk*32 + (lk-256).
__global__ void prep_kernel(const float* __restrict__ bw,
                            const float* __restrict__ sw,
                            const float* __restrict__ ss,
                            float* __restrict__ Wt, int F) {
    int id = blockIdx.x * blockDim.x + threadIdx.x;
    int total = 9 * F * NOUT;
    if (id >= total) return;
    int o  = id & 255;
    int kg = id >> 8;
    int chunk = kg / KC;
    int lk    = kg % KC;
    float v;
    if (lk < 256) {
        int f = chunk * FC + (lk >> 3);
        int j = lk & 7;
        v = sw[(o * F + f) * 8 + j] * ss[o * F + f];
    } else {
        int f = chunk * FC + (lk - 256);
        v = bw[o * F + f];
    }
    Wt[(size_t)kg * NOUT + o] = v;
}

// ---------------------------------------------------------------------------
// Layer GEMM: out(N,256) = Aug(h) (N,9F) @ Wt (9F,256).
// Block: 64 rows x 256 cols, 256 threads, 8x8 register tile each.
// A-tile expanded on the fly into LDS, transposed: A[k][row].
template <int F>
__global__ __launch_bounds__(256, 2)
void layer_kernel(const float* __restrict__ hin,
                  const float* __restrict__ Wt,
                  float* __restrict__ out) {
    constexpr int NCHUNK = F / FC;
    __shared__ float A[KC][BM];      // 288*64*4 = 73728 B

    const int row0 = blockIdx.x * BM;
    const int t  = threadIdx.x;
    const int tx = t & 31;           // col group: cols tx*8 .. +7
    const int ty = t >> 5;           // row group: rows ty*8 .. +7

    float acc[8][8];
#pragma unroll
    for (int i = 0; i < 8; ++i)
#pragma unroll
        for (int j = 0; j < 8; ++j) acc[i][j] = 0.0f;

    for (int c = 0; c < NCHUNK; ++c) {
        __syncthreads();   // previous chunk's reads done before overwrite
        // ---- expansion: 64 rows x 32 feats -> A[288][64] ----
        // elem e = f*64 + r ; lane-contiguous in r => conflict-free LDS writes
#pragma unroll
        for (int i = 0; i < (BM * FC) / 256; ++i) {
            int e = t + 256 * i;
            int r = e & 63;
            int f = e >> 6;
            float x = hin[(size_t)(row0 + r) * F + c * FC + f];
            float b[8];
            spline8(x, b);
#pragma unroll
            for (int j = 0; j < 8; ++j) A[f * 8 + j][r] = b[j];
            A[256 + f][r] = silu_f(x);
        }
        __syncthreads();

        // ---- accumulate over 288 k values ----
        const float* wp = Wt + (size_t)c * KC * NOUT + tx * 8;
#pragma unroll 4
        for (int k = 0; k < KC; ++k) {
            float4 w0 = *(const float4*)(wp + (size_t)k * NOUT);
            float4 w1 = *(const float4*)(wp + (size_t)k * NOUT + 4);
            float4 a0 = *(const float4*)&A[k][ty * 8];
            float4 a1 = *(const float4*)&A[k][ty * 8 + 4];
            float av[8] = {a0.x, a0.y, a0.z, a0.w, a1.x, a1.y, a1.z, a1.w};
            float wv[8] = {w0.x, w0.y, w0.z, w0.w, w1.x, w1.y, w1.z, w1.w};
#pragma unroll
            for (int rr = 0; rr < 8; ++rr)
#pragma unroll
                for (int cc = 0; cc < 8; ++cc)
                    acc[rr][cc] = fmaf(av[rr], wv[cc], acc[rr][cc]);
        }
    }

    // ---- epilogue ----
#pragma unroll
    for (int rr = 0; rr < 8; ++rr) {
        int row = row0 + ty * 8 + rr;
        float4 o0 = make_float4(acc[rr][0], acc[rr][1], acc[rr][2], acc[rr][3]);
        float4 o1 = make_float4(acc[rr][4], acc[rr][5], acc[rr][6], acc[rr][7]);
        *(float4*)(out + (size_t)row * NOUT + tx * 8)     = o0;
        *(float4*)(out + (size_t)row * NOUT + tx * 8 + 4) = o1;
    }
}

// ---------------------------------------------------------------------------
// Final layer: n_out = 1. One wave per row, shuffle-reduce.
__global__ void layer3_kernel(const float* __restrict__ hin,
                              const float* __restrict__ sw,
                              const float* __restrict__ ss,
                              const float* __restrict__ bw,
                              float* __restrict__ out) {
    int gid  = blockIdx.x * blockDim.x + threadIdx.x;
    int row  = gid >> 6;
    int lane = gid & 63;
    if (row >= N_PTS) return;
    float acc = 0.0f;
#pragma unroll
    for (int it = 0; it < 4; ++it) {
        int f = lane + it * 64;
        float x = hin[(size_t)row * 256 + f];
        float b[8];
        spline8(x, b);
        float dot = 0.0f;
#pragma unroll
        for (int j = 0; j < 8; ++j) dot = fmaf(b[j], sw[f * 8 + j], dot);
        acc = fmaf(dot, ss[f], acc);
        acc = fmaf(silu_f(x), bw[f], acc);
    }
#pragma unroll
    for (int off = 32; off > 0; off >>= 1) acc += __shfl_down(acc, off);
    if (lane == 0) out[row] = acc;
}

// ---------------------------------------------------------------------------
extern "C" void kernel_launch(void* const* d_in, const int* in_sizes, int n_in,
                              void* d_out, int out_size, void* d_ws, size_t ws_size,
                              hipStream_t stream) {
    const float* x    = (const float*)d_in[0];
    const float* freq = (const float*)d_in[1];
    const float* bw0  = (const float*)d_in[2];
    const float* sw0  = (const float*)d_in[3];
    const float* ss0  = (const float*)d_in[4];
    const float* bw1  = (const float*)d_in[5];
    const float* sw1  = (const float*)d_in[6];
    const float* ss1  = (const float*)d_in[7];
    const float* bw2  = (const float*)d_in[8];
    const float* sw2  = (const float*)d_in[9];
    const float* ss2  = (const float*)d_in[10];
    const float* bw3  = (const float*)d_in[11];
    const float* sw3  = (const float*)d_in[12];
    const float* ss3  = (const float*)d_in[13];

    float* ws  = (float*)d_ws;
    float* Wt0 = ws + WT0_OFF;
    float* Wt1 = ws + WT1_OFF;
    float* Wt2 = ws + WT2_OFF;
    float* h0  = ws + H0_OFF;
    float* hA  = ws + HA_OFF;
    float* hB  = ws + HB_OFF;
    float* outp = (float*)d_out;

    // weight folding (independent of activations; stream-ordered anyway)
    prep_kernel<<<(9 * 32 * NOUT + 255) / 256, 256, 0, stream>>>(bw0, sw0, ss0, Wt0, 32);
    prep_kernel<<<(9 * 256 * NOUT + 255) / 256, 256, 0, stream>>>(bw1, sw1, ss1, Wt1, 256);
    prep_kernel<<<(9 * 256 * NOUT + 255) / 256, 256, 0, stream>>>(bw2, sw2, ss2, Wt2, 256);

    encode_kernel<<<(N_PTS + 255) / 256, 256, 0, stream>>>(x, freq, h0);

    layer_kernel<32><<<N_PTS / BM, 256, 0, stream>>>(h0, Wt0, hA);
    layer_kernel<256><<<N_PTS / BM, 256, 0, stream>>>(hA, Wt1, hB);
    layer_kernel<256><<<N_PTS / BM, 256, 0, stream>>>(hB, Wt2, hA);

    layer3_kernel<<<(N_PTS * 64) / 256, 256, 0, stream>>>(hA, sw3, ss3, bw3, outp);
}

// Round 2
// 588.998 us; speedup vs baseline: 1.9460x; 1.9460x over previous
//
#include <hip/hip_runtime.h>
#include <math.h>
#include <stdint.h>

// ---------------------------------------------------------------------------
// KAN forward, split-bf16 MFMA version.
//   Augmented-K GEMM per layer: K = 9F (8 spline bases + 1 silu per feature).
//   A (activations expanded) generated IN REGISTERS as MFMA A-fragments.
//   W prefolded, split into bf16 hi/lo pair, staged via global_load_lds.
//   3-product split emulation: Ah*Wh + Al*Wh + Ah*Wl  (error ~2^-18 rel).
// ---------------------------------------------------------------------------

#define N_PTS 32768

using short8 = __attribute__((ext_vector_type(8))) short;
using f32x4  = __attribute__((ext_vector_type(4))) float;

union Frag { short8 v; uint32_t u[4]; };

__device__ __forceinline__ uint32_t bf16rne(float f) {
    uint32_t u = __float_as_uint(f);
    return (u + 0x7FFFu + ((u >> 16) & 1u)) >> 16;
}
__device__ __forceinline__ float bf16tof(uint32_t h) { return __uint_as_float(h << 16); }

// async global->LDS, 16B per lane (wave-uniform base + lane*16 semantics)
__device__ __forceinline__ void gld16(const void* g, void* lds) {
    __builtin_amdgcn_global_load_lds(
        (const __attribute__((address_space(1))) void*)(uintptr_t)g,
        (__attribute__((address_space(3))) void*)(uint32_t)(uintptr_t)lds,
        16, 0, 0);
}

// ---------------------------------------------------------------------------
// fast uniform cubic B-spline: 4 nonzero cardinal segments, scatter to 8 slots
// t = (x+2.2)/0.4 ; i = floor(t) ; w = t - i ; nonzero j = i-3..i
__device__ __forceinline__ void build_basis_frag(float x, Frag& ah, Frag& al) {
    float t  = (x + 2.2f) * 2.5f;
    float fl = floorf(t);
    int   i  = (int)fl;
    float w  = t - fl;
    float w2 = w * w, w3 = w2 * w;
    const float s = 1.0f / 6.0f;
    float q0 = w3 * s;                                   // j == i
    float q1 = (-3.f * w3 + 3.f * w2 + 3.f * w + 1.f) * s; // j == i-1
    float q2 = (3.f * w3 - 6.f * w2 + 4.f) * s;          // j == i-2
    float omw = 1.f - w;
    float q3 = omw * omw * omw * s;                      // j == i-3
#pragma unroll
    for (int p = 0; p < 4; ++p) {
        const int j0 = p * 2, j1 = p * 2 + 1;
        float v0 = (i == j0) ? q0 : (i == j0 + 1) ? q1 : (i == j0 + 2) ? q2 : (i == j0 + 3) ? q3 : 0.f;
        float v1 = (i == j1) ? q0 : (i == j1 + 1) ? q1 : (i == j1 + 2) ? q2 : (i == j1 + 3) ? q3 : 0.f;
        uint32_t h0 = bf16rne(v0), h1 = bf16rne(v1);
        uint32_t r0 = bf16rne(v0 - bf16tof(h0));
        uint32_t r1 = bf16rne(v1 - bf16tof(h1));
        ah.u[p] = h0 | (h1 << 16);
        al.u[p] = r0 | (r1 << 16);
    }
}

__device__ __forceinline__ void build_silu_frag(const float* __restrict__ xp, Frag& ah, Frag& al) {
    float4 a = *(const float4*)xp;
    float4 b = *(const float4*)(xp + 4);
    float xs[8] = {a.x, a.y, a.z, a.w, b.x, b.y, b.z, b.w};
#pragma unroll
    for (int p = 0; p < 4; ++p) {
        float x0 = xs[p * 2], x1 = xs[p * 2 + 1];
        float v0 = x0 / (1.f + __expf(-x0));
        float v1 = x1 / (1.f + __expf(-x1));
        uint32_t h0 = bf16rne(v0), h1 = bf16rne(v1);
        uint32_t r0 = bf16rne(v0 - bf16tof(h0));
        uint32_t r1 = bf16rne(v1 - bf16tof(h1));
        ah.u[p] = h0 | (h1 << 16);
        al.u[p] = r0 | (r1 << 16);
    }
}

// ---------------------------------------------------------------------------
__global__ void encode_kernel(const float* __restrict__ x,
                              const float* __restrict__ freq,
                              float* __restrict__ h0) {
    int n = blockIdx.x * blockDim.x + threadIdx.x;
    if (n >= N_PTS) return;
    float xv = x[n];
#pragma unroll
    for (int l = 0; l < 16; ++l) {
        float e = xv * freq[l];
        h0[n * 32 + l]      = sinf(e);
        h0[n * 32 + 16 + l] = cosf(e);
    }
}

// Fold sw*ss (k = f*8+j) and bw (k = 8F+f) into split-bf16 pair, layout
// Wh/Wl[(k>>3)][col][k&7] so fragment reads are ds_read_b128-contiguous and
// chunk staging (32 k x 256 cols = 16 KB) is flat-contiguous.
__global__ void prep_kernel(const float* __restrict__ bw,
                            const float* __restrict__ sw,
                            const float* __restrict__ ss,
                            short* __restrict__ Wh, short* __restrict__ Wl, int F) {
    int id = blockIdx.x * blockDim.x + threadIdx.x;
    int K = 9 * F;
    if (id >= K * 256) return;
    int col = id & 255;
    int k   = id >> 8;
    float wv;
    if (k < 8 * F) {
        int f = k >> 3, j = k & 7;
        wv = sw[(col * F + f) * 8 + j] * ss[col * F + f];
    } else {
        int f = k - 8 * F;
        wv = bw[col * F + f];
    }
    uint32_t hh = bf16rne(wv);
    uint32_t ll = bf16rne(wv - bf16tof(hh));
    size_t idx = ((size_t)(k >> 3) * 256 + col) * 8 + (k & 7);
    Wh[idx] = (short)hh;
    Wl[idx] = (short)ll;
}

// ---------------------------------------------------------------------------
// out(N,256) = Aug(h)(N,9F) @ W(9F,256), split-bf16 MFMA.
// Block: 64 rows x 256 cols, 4 waves; wave = 32 rows (2 row-tiles) x 128 cols
// (8 col-tiles). A-frags in registers; W chunk (32k x 256) double-buffered in
// LDS via global_load_lds width-16.
template <int F>
__global__ __launch_bounds__(256, 2)
void layer_mfma(const float* __restrict__ hin,
                const short* __restrict__ Wh, const short* __restrict__ Wl,
                float* __restrict__ out) {
    constexpr int KBC = F / 4;    // basis chunks (8F/32)
    constexpr int KSC = F / 32;   // silu chunks
    constexpr int NC  = KBC + KSC;
    __shared__ short WB[2][2][8192];   // [buf][h/l][32k x 256col] = 64 KB

    const int tid  = threadIdx.x;
    const int wv   = tid >> 6;
    const int wy   = wv >> 1, wx = wv & 1;
    const int lane = tid & 63;
    const int lr   = lane & 15, quad = lane >> 4;
    const int row0 = blockIdx.x * 64;

    f32x4 acc[2][8];
#pragma unroll
    for (int a1 = 0; a1 < 2; ++a1)
#pragma unroll
        for (int a2 = 0; a2 < 8; ++a2) acc[a1][a2] = (f32x4){0.f, 0.f, 0.f, 0.f};

    // stage chunk 0 into buf 0
    {
        const size_t gof = 0;
#pragma unroll
        for (int i = 0; i < 4; ++i) {
            int e = tid * 8 + i * 2048;
            gld16(Wh + gof + e, &WB[0][0][e]);
            gld16(Wl + gof + e, &WB[0][1][e]);
        }
    }
    __syncthreads();

    for (int c = 0; c < NC; ++c) {
        const int cur = c & 1;
        if (c + 1 < NC) {   // prefetch next chunk into other buffer
            const size_t gof = (size_t)(c + 1) * 8192;
#pragma unroll
            for (int i = 0; i < 4; ++i) {
                int e = tid * 8 + i * 2048;
                gld16(Wh + gof + e, &WB[cur ^ 1][0][e]);
                gld16(Wl + gof + e, &WB[cur ^ 1][1][e]);
            }
        }

        // ---- A fragments (registers) ----
        Frag ah[2], al[2];
        if (c < KBC) {
            const int f = c * 4 + quad;
#pragma unroll
            for (int rt = 0; rt < 2; ++rt) {
                int r = row0 + wy * 32 + rt * 16 + lr;
                float x = hin[(size_t)r * F + f];
                build_basis_frag(x, ah[rt], al[rt]);
            }
        } else {
            const int fb = (c - KBC) * 32 + quad * 8;
#pragma unroll
            for (int rt = 0; rt < 2; ++rt) {
                int r = row0 + wy * 32 + rt * 16 + lr;
                build_silu_frag(&hin[(size_t)r * F + fb], ah[rt], al[rt]);
            }
        }

        // ---- MFMA over 8 col-tiles ----
        const short* WHp = WB[cur][0];
        const short* WLp = WB[cur][1];
#pragma unroll
        for (int ct = 0; ct < 8; ++ct) {
            int col = wx * 128 + ct * 16 + lr;
            int off = (quad * 256 + col) * 8;
            Frag wh, wl;
            wh.v = *(const short8*)&WHp[off];
            wl.v = *(const short8*)&WLp[off];
#pragma unroll
            for (int rt = 0; rt < 2; ++rt) {
                acc[rt][ct] = __builtin_amdgcn_mfma_f32_16x16x32_bf16(ah[rt].v, wh.v, acc[rt][ct], 0, 0, 0);
                acc[rt][ct] = __builtin_amdgcn_mfma_f32_16x16x32_bf16(al[rt].v, wh.v, acc[rt][ct], 0, 0, 0);
                acc[rt][ct] = __builtin_amdgcn_mfma_f32_16x16x32_bf16(ah[rt].v, wl.v, acc[rt][ct], 0, 0, 0);
            }
        }
        __syncthreads();
    }

    // ---- epilogue: C/D layout col=lane&15, row=quad*4+reg ----
#pragma unroll
    for (int rt = 0; rt < 2; ++rt) {
        const int rbase = row0 + wy * 32 + rt * 16 + quad * 4;
#pragma unroll
        for (int ct = 0; ct < 8; ++ct) {
            const int colg = wx * 128 + ct * 16 + lr;
#pragma unroll
            for (int rg = 0; rg < 4; ++rg)
                out[(size_t)(rbase + rg) * 256 + colg] = acc[rt][ct][rg];
        }
    }
}

// ---------------------------------------------------------------------------
// Final layer (n_out=1), fp32 wave-reduce (unchanged from passing round 1).
__device__ __forceinline__ float knotf(int j) { return (float)(j - 3) * 0.4f - 1.0f; }

__device__ __forceinline__ void spline8(float x, float b[8]) {
    float b0[11];
#pragma unroll
    for (int j = 0; j < 11; ++j)
        b0[j] = (x >= knotf(j) && x < knotf(j + 1)) ? 1.0f : 0.0f;
    float b1[10];
#pragma unroll
    for (int j = 0; j < 10; ++j)
        b1[j] = (x - knotf(j)) * (1.0f / (knotf(j + 1) - knotf(j))) * b0[j]
              + (knotf(j + 2) - x) * (1.0f / (knotf(j + 2) - knotf(j + 1))) * b0[j + 1];
    float b2[9];
#pragma unroll
    for (int j = 0; j < 9; ++j)
        b2[j] = (x - knotf(j)) * (1.0f / (knotf(j + 2) - knotf(j))) * b1[j]
              + (knotf(j + 3) - x) * (1.0f / (knotf(j + 3) - knotf(j + 1))) * b1[j + 1];
#pragma unroll
    for (int j = 0; j < 8; ++j)
        b[j]  = (x - knotf(j)) * (1.0f / (knotf(j + 3) - knotf(j))) * b2[j]
              + (knotf(j + 4) - x) * (1.0f / (knotf(j + 4) - knotf(j + 1))) * b2[j + 1];
}

__global__ void layer3_kernel(const float* __restrict__ hin,
                              const float* __restrict__ sw,
                              const float* __restrict__ ss,
                              const float* __restrict__ bw,
                              float* __restrict__ out) {
    int gid  = blockIdx.x * blockDim.x + threadIdx.x;
    int row  = gid >> 6;
    int lane = gid & 63;
    if (row >= N_PTS) return;
    float acc = 0.0f;
#pragma unroll
    for (int it = 0; it < 4; ++it) {
        int f = lane + it * 64;
        float x = hin[(size_t)row * 256 + f];
        float b[8];
        spline8(x, b);
        float dot = 0.0f;
#pragma unroll
        for (int j = 0; j < 8; ++j) dot = fmaf(b[j], sw[f * 8 + j], dot);
        acc = fmaf(dot, ss[f], acc);
        acc = fmaf(x / (1.0f + expf(-x)), bw[f], acc);
    }
#pragma unroll
    for (int off = 32; off > 0; off >>= 1) acc += __shfl_down(acc, off);
    if (lane == 0) out[row] = acc;
}

// ---------------------------------------------------------------------------
// ws layout (bytes)
#define WH0_OFF 0u
#define WL0_OFF (WH0_OFF + 147456u)      // 288*256*2
#define WH1_OFF (WL0_OFF + 147456u)
#define WL1_OFF (WH1_OFF + 1179648u)     // 2304*256*2
#define WH2_OFF (WL1_OFF + 1179648u)
#define WL2_OFF (WH2_OFF + 1179648u)
#define H0_OFF  (WL2_OFF + 1179648u)     // 32768*32*4
#define HA_OFF  (H0_OFF + 4194304u)      // 32768*256*4
#define HB_OFF  (HA_OFF + 33554432u)
// total = 76,316,672 B

extern "C" void kernel_launch(void* const* d_in, const int* in_sizes, int n_in,
                              void* d_out, int out_size, void* d_ws, size_t ws_size,
                              hipStream_t stream) {
    const float* x    = (const float*)d_in[0];
    const float* freq = (const float*)d_in[1];
    const float* bw0  = (const float*)d_in[2];
    const float* sw0  = (const float*)d_in[3];
    const float* ss0  = (const float*)d_in[4];
    const float* bw1  = (const float*)d_in[5];
    const float* sw1  = (const float*)d_in[6];
    const float* ss1  = (const float*)d_in[7];
    const float* bw2  = (const float*)d_in[8];
    const float* sw2  = (const float*)d_in[9];
    const float* ss2  = (const float*)d_in[10];
    const float* bw3  = (const float*)d_in[11];
    const float* sw3  = (const float*)d_in[12];
    const float* ss3  = (const float*)d_in[13];

    char* ws = (char*)d_ws;
    short* Wh0 = (short*)(ws + WH0_OFF);
    short* Wl0 = (short*)(ws + WL0_OFF);
    short* Wh1 = (short*)(ws + WH1_OFF);
    short* Wl1 = (short*)(ws + WL1_OFF);
    short* Wh2 = (short*)(ws + WH2_OFF);
    short* Wl2 = (short*)(ws + WL2_OFF);
    float* h0 = (float*)(ws + H0_OFF);
    float* hA = (float*)(ws + HA_OFF);
    float* hB = (float*)(ws + HB_OFF);
    float* outp = (float*)d_out;

    prep_kernel<<<288, 256, 0, stream>>>(bw0, sw0, ss0, Wh0, Wl0, 32);
    prep_kernel<<<2304, 256, 0, stream>>>(bw1, sw1, ss1, Wh1, Wl1, 256);
    prep_kernel<<<2304, 256, 0, stream>>>(bw2, sw2, ss2, Wh2, Wl2, 256);

    encode_kernel<<<(N_PTS + 255) / 256, 256, 0, stream>>>(x, freq, h0);

    layer_mfma<32><<<N_PTS / 64, 256, 0, stream>>>(h0, Wh0, Wl0, hA);
    layer_mfma<256><<<N_PTS / 64, 256, 0, stream>>>(hA, Wh1, Wl1, hB);
    layer_mfma<256><<<N_PTS / 64, 256, 0, stream>>>(hB, Wh2, Wl2, hA);

    layer3_kernel<<<(N_PTS * 64) / 256, 256, 0, stream>>>(hA, sw3, ss3, bw3, outp);
}

// Round 3
// 395.921 us; speedup vs baseline: 2.8950x; 1.4877x over previous
//
#include <hip/hip_runtime.h>
#include <math.h>
#include <stdint.h>

// ---------------------------------------------------------------------------
// KAN forward, split-bf16 MFMA version, round 3: cheap fragment builds.
//   Augmented-K GEMM per layer: K = 9F (8 spline bases + 1 silu per feature).
//   A generated IN REGISTERS as MFMA A-fragments via trunc-split + v_perm.
//   W prefolded, split into bf16 hi/lo pair, staged via global_load_lds.
//   3-product split emulation: Ah*Wh + Al*Wh + Ah*Wl  (error ~2^-16 rel).
// ---------------------------------------------------------------------------

#define N_PTS 32768

using short8 = __attribute__((ext_vector_type(8))) short;
using f32x4  = __attribute__((ext_vector_type(4))) float;

union Frag { short8 v; uint32_t u[4]; };

__device__ __forceinline__ uint32_t bf16rne(float f) {
    uint32_t u = __float_as_uint(f);
    return (u + 0x7FFFu + ((u >> 16) & 1u)) >> 16;
}
__device__ __forceinline__ float bf16tof(uint32_t h) { return __uint_as_float(h << 16); }

// pack bf16-trunc(x0) into lo16, bf16-trunc(x1) into hi16 — one v_perm_b32
__device__ __forceinline__ uint32_t pkhi(uint32_t x0, uint32_t x1) {
    return __builtin_amdgcn_perm(x1, x0, 0x07060302u);
}

// async global->LDS, 16B per lane (wave-uniform base + lane*16 semantics)
__device__ __forceinline__ void gld16(const void* g, void* lds) {
    __builtin_amdgcn_global_load_lds(
        (const __attribute__((address_space(1))) void*)(uintptr_t)g,
        (__attribute__((address_space(3))) void*)(uint32_t)(uintptr_t)lds,
        16, 0, 0);
}

// ---------------------------------------------------------------------------
// fast uniform cubic B-spline, trunc-split bf16 fragments.
// t = (x+2.2)/0.4 ; i = floor(t) ; slot j nonzero for j = i-3..i with value
// q_{i-j}.  Pair p (slots 2p,2p+1) selected from 5 packed candidates by i-2p.
__device__ __forceinline__ void build_basis_frag(float x, Frag& ah, Frag& al) {
    float t  = (x + 2.2f) * 2.5f;
    float fl = floorf(t);
    int   i  = (int)fl;
    float w  = t - fl;
    float w2 = w * w, w3 = w2 * w;
    const float s = 1.0f / 6.0f;
    float q0 = w3 * s;                                     // d == 0 (j == i)
    float q1 = (-3.f * w3 + 3.f * w2 + 3.f * w + 1.f) * s; // d == 1
    float q2 = (3.f * w3 - 6.f * w2 + 4.f) * s;            // d == 2
    float omw = 1.f - w;
    float q3 = omw * omw * omw * s;                        // d == 3
    uint32_t u0 = __float_as_uint(q0), u1 = __float_as_uint(q1);
    uint32_t u2 = __float_as_uint(q2), u3 = __float_as_uint(q3);
    // exact residual of the truncated head, then bf16-trunc via perm
    uint32_t r0 = __float_as_uint(q0 - __uint_as_float(u0 & 0xFFFF0000u));
    uint32_t r1 = __float_as_uint(q1 - __uint_as_float(u1 & 0xFFFF0000u));
    uint32_t r2 = __float_as_uint(q2 - __uint_as_float(u2 & 0xFFFF0000u));
    uint32_t r3 = __float_as_uint(q3 - __uint_as_float(u3 & 0xFFFF0000u));
    uint32_t PH0 = pkhi(u0, 0u), PH1 = pkhi(u1, u0), PH2 = pkhi(u2, u1),
             PH3 = pkhi(u3, u2), PH4 = pkhi(0u, u3);
    uint32_t PL0 = pkhi(r0, 0u), PL1 = pkhi(r1, r0), PL2 = pkhi(r2, r1),
             PL3 = pkhi(r3, r2), PL4 = pkhi(0u, r3);
#pragma unroll
    for (int p = 0; p < 4; ++p) {
        bool c0 = (i == 2 * p), c1 = (i == 2 * p + 1), c2 = (i == 2 * p + 2),
             c3 = (i == 2 * p + 3), c4 = (i == 2 * p + 4);
        ah.u[p] = c0 ? PH0 : c1 ? PH1 : c2 ? PH2 : c3 ? PH3 : c4 ? PH4 : 0u;
        al.u[p] = c0 ? PL0 : c1 ? PL1 : c2 ? PL2 : c3 ? PL3 : c4 ? PL4 : 0u;
    }
}

__device__ __forceinline__ void build_silu_frag(const float* __restrict__ xp, Frag& ah, Frag& al) {
    float4 a = *(const float4*)xp;
    float4 b = *(const float4*)(xp + 4);
    float xs[8] = {a.x, a.y, a.z, a.w, b.x, b.y, b.z, b.w};
#pragma unroll
    for (int p = 0; p < 4; ++p) {
        float x0 = xs[p * 2], x1 = xs[p * 2 + 1];
        float v0 = x0 / (1.f + __expf(-x0));
        float v1 = x1 / (1.f + __expf(-x1));
        uint32_t w0 = __float_as_uint(v0), w1 = __float_as_uint(v1);
        uint32_t l0 = __float_as_uint(v0 - __uint_as_float(w0 & 0xFFFF0000u));
        uint32_t l1 = __float_as_uint(v1 - __uint_as_float(w1 & 0xFFFF0000u));
        ah.u[p] = pkhi(w0, w1);
        al.u[p] = pkhi(l0, l1);
    }
}

// ---------------------------------------------------------------------------
__global__ void encode_kernel(const float* __restrict__ x,
                              const float* __restrict__ freq,
                              float* __restrict__ h0) {
    int n = blockIdx.x * blockDim.x + threadIdx.x;
    if (n >= N_PTS) return;
    float xv = x[n];
#pragma unroll
    for (int l = 0; l < 16; ++l) {
        float e = xv * freq[l];
        h0[n * 32 + l]      = sinf(e);
        h0[n * 32 + 16 + l] = cosf(e);
    }
}

// Fold sw*ss (k = f*8+j) and bw (k = 8F+f) into split-bf16 pair, layout
// Wh/Wl[(k>>3)][col][k&7] so fragment reads are ds_read_b128-contiguous and
// chunk staging (32 k x 256 cols = 16 KB) is flat-contiguous.
__global__ void prep_kernel(const float* __restrict__ bw,
                            const float* __restrict__ sw,
                            const float* __restrict__ ss,
                            short* __restrict__ Wh, short* __restrict__ Wl, int F) {
    int id = blockIdx.x * blockDim.x + threadIdx.x;
    int K = 9 * F;
    if (id >= K * 256) return;
    int col = id & 255;
    int k   = id >> 8;
    float wv;
    if (k < 8 * F) {
        int f = k >> 3, j = k & 7;
        wv = sw[(col * F + f) * 8 + j] * ss[col * F + f];
    } else {
        int f = k - 8 * F;
        wv = bw[col * F + f];
    }
    uint32_t hh = bf16rne(wv);
    uint32_t ll = bf16rne(wv - bf16tof(hh));
    size_t idx = ((size_t)(k >> 3) * 256 + col) * 8 + (k & 7);
    Wh[idx] = (short)hh;
    Wl[idx] = (short)ll;
}

// ---------------------------------------------------------------------------
// out(N,256) = Aug(h)(N,9F) @ W(9F,256), split-bf16 MFMA.
// Block: 64 rows x 256 cols, 4 waves; wave = 32 rows (2 row-tiles) x 128 cols
// (8 col-tiles). A-frags in registers; W chunk (32k x 256) double-buffered in
// LDS via global_load_lds width-16. Activation scalar prefetched 1 chunk ahead.
template <int F>
__global__ __launch_bounds__(256, 2)
void layer_mfma(const float* __restrict__ hin,
                const short* __restrict__ Wh, const short* __restrict__ Wl,
                float* __restrict__ out) {
    constexpr int KBC = F / 4;    // basis chunks (8F/32)
    constexpr int KSC = F / 32;   // silu chunks
    constexpr int NC  = KBC + KSC;
    __shared__ short WB[2][2][8192];   // [buf][h/l][32k x 256col] = 64 KB

    const int tid  = threadIdx.x;
    const int wv   = tid >> 6;
    const int wy   = wv >> 1, wx = wv & 1;
    const int lane = tid & 63;
    const int lr   = lane & 15, quad = lane >> 4;
    const int row0 = blockIdx.x * 64;

    f32x4 acc[2][8];
#pragma unroll
    for (int a1 = 0; a1 < 2; ++a1)
#pragma unroll
        for (int a2 = 0; a2 < 8; ++a2) acc[a1][a2] = (f32x4){0.f, 0.f, 0.f, 0.f};

    // stage chunk 0 into buf 0
    {
#pragma unroll
        for (int i = 0; i < 4; ++i) {
            int e = tid * 8 + i * 2048;
            gld16(Wh + e, &WB[0][0][e]);
            gld16(Wl + e, &WB[0][1][e]);
        }
    }

    // preload x for chunk 0 (basis region)
    float xreg[2];
#pragma unroll
    for (int rt = 0; rt < 2; ++rt) {
        int r = row0 + wy * 32 + rt * 16 + lr;
        xreg[rt] = hin[(size_t)r * F + quad];
    }
    __syncthreads();

    for (int c = 0; c < NC; ++c) {
        const int cur = c & 1;
        if (c + 1 < NC) {   // prefetch next W chunk into other buffer
            const size_t gof = (size_t)(c + 1) * 8192;
#pragma unroll
            for (int i = 0; i < 4; ++i) {
                int e = tid * 8 + i * 2048;
                gld16(Wh + gof + e, &WB[cur ^ 1][0][e]);
                gld16(Wl + gof + e, &WB[cur ^ 1][1][e]);
            }
        }

        // ---- A fragments (registers) ----
        Frag ah[2], al[2];
        if (c < KBC) {
            float xcur[2] = {xreg[0], xreg[1]};
            if (c + 1 < KBC) {   // prefetch next basis-chunk activation
                const int fn = (c + 1) * 4 + quad;
#pragma unroll
                for (int rt = 0; rt < 2; ++rt) {
                    int r = row0 + wy * 32 + rt * 16 + lr;
                    xreg[rt] = hin[(size_t)r * F + fn];
                }
            }
#pragma unroll
            for (int rt = 0; rt < 2; ++rt)
                build_basis_frag(xcur[rt], ah[rt], al[rt]);
        } else {
            const int fb = (c - KBC) * 32 + quad * 8;
#pragma unroll
            for (int rt = 0; rt < 2; ++rt) {
                int r = row0 + wy * 32 + rt * 16 + lr;
                build_silu_frag(&hin[(size_t)r * F + fb], ah[rt], al[rt]);
            }
        }

        // ---- MFMA over 8 col-tiles ----
        const short* WHp = WB[cur][0];
        const short* WLp = WB[cur][1];
#pragma unroll
        for (int ct = 0; ct < 8; ++ct) {
            int col = wx * 128 + ct * 16 + lr;
            int off = (quad * 256 + col) * 8;
            Frag wh, wl;
            wh.v = *(const short8*)&WHp[off];
            wl.v = *(const short8*)&WLp[off];
#pragma unroll
            for (int rt = 0; rt < 2; ++rt) {
                acc[rt][ct] = __builtin_amdgcn_mfma_f32_16x16x32_bf16(ah[rt].v, wh.v, acc[rt][ct], 0, 0, 0);
                acc[rt][ct] = __builtin_amdgcn_mfma_f32_16x16x32_bf16(al[rt].v, wh.v, acc[rt][ct], 0, 0, 0);
                acc[rt][ct] = __builtin_amdgcn_mfma_f32_16x16x32_bf16(ah[rt].v, wl.v, acc[rt][ct], 0, 0, 0);
            }
        }
        __syncthreads();
    }

    // ---- epilogue: C/D layout col=lane&15, row=quad*4+reg ----
#pragma unroll
    for (int rt = 0; rt < 2; ++rt) {
        const int rbase = row0 + wy * 32 + rt * 16 + quad * 4;
#pragma unroll
        for (int ct = 0; ct < 8; ++ct) {
            const int colg = wx * 128 + ct * 16 + lr;
#pragma unroll
            for (int rg = 0; rg < 4; ++rg)
                out[(size_t)(rbase + rg) * 256 + colg] = acc[rt][ct][rg];
        }
    }
}

// ---------------------------------------------------------------------------
// Final layer (n_out=1), fp32 wave-reduce.
__device__ __forceinline__ float knotf(int j) { return (float)(j - 3) * 0.4f - 1.0f; }

__device__ __forceinline__ void spline8(float x, float b[8]) {
    float b0[11];
#pragma unroll
    for (int j = 0; j < 11; ++j)
        b0[j] = (x >= knotf(j) && x < knotf(j + 1)) ? 1.0f : 0.0f;
    float b1[10];
#pragma unroll
    for (int j = 0; j < 10; ++j)
        b1[j] = (x - knotf(j)) * (1.0f / (knotf(j + 1) - knotf(j))) * b0[j]
              + (knotf(j + 2) - x) * (1.0f / (knotf(j + 2) - knotf(j + 1))) * b0[j + 1];
    float b2[9];
#pragma unroll
    for (int j = 0; j < 9; ++j)
        b2[j] = (x - knotf(j)) * (1.0f / (knotf(j + 2) - knotf(j))) * b1[j]
              + (knotf(j + 3) - x) * (1.0f / (knotf(j + 3) - knotf(j + 1))) * b1[j + 1];
#pragma unroll
    for (int j = 0; j < 8; ++j)
        b[j]  = (x - knotf(j)) * (1.0f / (knotf(j + 3) - knotf(j))) * b2[j]
              + (knotf(j + 4) - x) * (1.0f / (knotf(j + 4) - knotf(j + 1))) * b2[j + 1];
}

__global__ void layer3_kernel(const float* __restrict__ hin,
                              const float* __restrict__ sw,
                              const float* __restrict__ ss,
                              const float* __restrict__ bw,
                              float* __restrict__ out) {
    int gid  = blockIdx.x * blockDim.x + threadIdx.x;
    int row  = gid >> 6;
    int lane = gid & 63;
    if (row >= N_PTS) return;
    float acc = 0.0f;
#pragma unroll
    for (int it = 0; it < 4; ++it) {
        int f = lane + it * 64;
        float x = hin[(size_t)row * 256 + f];
        float b[8];
        spline8(x, b);
        float dot = 0.0f;
#pragma unroll
        for (int j = 0; j < 8; ++j) dot = fmaf(b[j], sw[f * 8 + j], dot);
        acc = fmaf(dot, ss[f], acc);
        acc = fmaf(x / (1.0f + expf(-x)), bw[f], acc);
    }
#pragma unroll
    for (int off = 32; off > 0; off >>= 1) acc += __shfl_down(acc, off);
    if (lane == 0) out[row] = acc;
}

// ---------------------------------------------------------------------------
// ws layout (bytes)
#define WH0_OFF 0u
#define WL0_OFF (WH0_OFF + 147456u)      // 288*256*2
#define WH1_OFF (WL0_OFF + 147456u)
#define WL1_OFF (WH1_OFF + 1179648u)     // 2304*256*2
#define WH2_OFF (WL1_OFF + 1179648u)
#define WL2_OFF (WH2_OFF + 1179648u)
#define H0_OFF  (WL2_OFF + 1179648u)     // 32768*32*4
#define HA_OFF  (H0_OFF + 4194304u)      // 32768*256*4
#define HB_OFF  (HA_OFF + 33554432u)
// total = 76,316,672 B

extern "C" void kernel_launch(void* const* d_in, const int* in_sizes, int n_in,
                              void* d_out, int out_size, void* d_ws, size_t ws_size,
                              hipStream_t stream) {
    const float* x    = (const float*)d_in[0];
    const float* freq = (const float*)d_in[1];
    const float* bw0  = (const float*)d_in[2];
    const float* sw0  = (const float*)d_in[3];
    const float* ss0  = (const float*)d_in[4];
    const float* bw1  = (const float*)d_in[5];
    const float* sw1  = (const float*)d_in[6];
    const float* ss1  = (const float*)d_in[7];
    const float* bw2  = (const float*)d_in[8];
    const float* sw2  = (const float*)d_in[9];
    const float* ss2  = (const float*)d_in[10];
    const float* bw3  = (const float*)d_in[11];
    const float* sw3  = (const float*)d_in[12];
    const float* ss3  = (const float*)d_in[13];

    char* ws = (char*)d_ws;
    short* Wh0 = (short*)(ws + WH0_OFF);
    short* Wl0 = (short*)(ws + WL0_OFF);
    short* Wh1 = (short*)(ws + WH1_OFF);
    short* Wl1 = (short*)(ws + WL1_OFF);
    short* Wh2 = (short*)(ws + WH2_OFF);
    short* Wl2 = (short*)(ws + WL2_OFF);
    float* h0 = (float*)(ws + H0_OFF);
    float* hA = (float*)(ws + HA_OFF);
    float* hB = (float*)(ws + HB_OFF);
    float* outp = (float*)d_out;

    prep_kernel<<<288, 256, 0, stream>>>(bw0, sw0, ss0, Wh0, Wl0, 32);
    prep_kernel<<<2304, 256, 0, stream>>>(bw1, sw1, ss1, Wh1, Wl1, 256);
    prep_kernel<<<2304, 256, 0, stream>>>(bw2, sw2, ss2, Wh2, Wl2, 256);

    encode_kernel<<<(N_PTS + 255) / 256, 256, 0, stream>>>(x, freq, h0);

    layer_mfma<32><<<N_PTS / 64, 256, 0, stream>>>(h0, Wh0, Wl0, hA);
    layer_mfma<256><<<N_PTS / 64, 256, 0, stream>>>(hA, Wh1, Wl1, hB);
    layer_mfma<256><<<N_PTS / 64, 256, 0, stream>>>(hB, Wh2, Wl2, hA);

    layer3_kernel<<<(N_PTS * 64) / 256, 256, 0, stream>>>(hA, sw3, ss3, bw3, outp);
}